// Round 5
// baseline (217.680 us; speedup 1.0000x reference)
//
#include <hip/hip_runtime.h>
#include <stdint.h>

// Problem constants (from reference): N=32768, H=6, W=8, C=14
constexpr int   kN          = 32768;
constexpr int   kCells      = 32768 * 6 * 8;      // 1,572,864 cells, 14 floats each
constexpr int   kC          = 14;

// Register-pipelined wave-private streaming:
//   chunk = 128 cells = 1792 floats/tensor = 448 float4/tensor
//   per lane per chunk: 7 float4 (O) + 7 float4 (G) = 14 dwordx4 loads, perfectly
//   coalesced (instr k: addr = base + k*1024 + lane*16)
//   LDS = 2 buffers x (O 1792 | G 1792 floats) = 28672 B per wave-block
//   grid = 1024 single-wave blocks (4/CU); 12 chunks each
//   1024 * 12 * 128 = 1,572,864 = kCells (exact, no bounds checks)
constexpr int   kSlots      = 1024;
constexpr int   kChunksSlot = 12;
constexpr int   kChunkCells = 128;
constexpr int   kChunkFlts  = kChunkCells * kC;        // 1792
constexpr int   kChunkVec4  = kChunkFlts / 4;          // 448
constexpr int   kSlotFlts   = kChunksSlot * kChunkFlts; // 21504

constexpr float LAMBDA_COORD = 8.0f;
constexpr float LAMBDA_NOOBJ = 1.0f;
constexpr float LAMBDA_CLASS = 0.7f;
constexpr float EPS          = 1e-10f;

__device__ __forceinline__ float iou_box(float bx, float by, float bsw, float bsh,
                                         float gx, float gy, float gsw, float gsh) {
    float w1 = bsw * bsw, h1 = bsh * bsh;
    float w2 = gsw * gsw, h2 = gsh * gsh;
    float left  = fmaxf(bx - 0.5f * w1, gx - 0.5f * w2);
    float right = fminf(bx + 0.5f * w1, gx + 0.5f * w2);
    float top   = fmaxf(by - 0.5f * h1, gy - 0.5f * h2);
    float bot   = fminf(by + 0.5f * h1, gy + 0.5f * h2);
    float inter = fmaxf(right - left, 0.0f) * fmaxf(bot - top, 0.0f);
    float uni   = w1 * h1 + w2 * h2 - inter;
    return inter / (uni + EPS);
}

__device__ __forceinline__ float cell_loss(const float* __restrict__ o,
                                           const float* __restrict__ g) {
    float o0=o[0],o1=o[1],o2=o[2],o3=o[3],o4=o[4],o5=o[5],o6=o[6],o7=o[7],o8=o[8],o9=o[9];
    float g0=g[0],g1=g[1],g2=g[2],g3=g[3],g4=g[4],g5=g[5],g6=g[6],g7=g[7],g8=g[8],g9=g[9];

    float obj   = (g4 > 0.0f) ? 1.0f : 0.0f;
    float noobj = 1.0f - obj;

    float iou0 = iou_box(o0, o1, o2, o3, g0, g1, g2, g3);
    float iou1 = iou_box(o5, o6, o7, o8, g0, g1, g2, g3);
    bool  s1   = iou1 > iou0;                  // argmax picks first on ties
    float max_iou = fmaxf(iou0, iou1);

    float pr0 = s1 ? o5 : o0;
    float pr1 = s1 ? o6 : o1;
    float pr2 = s1 ? o7 : o2;
    float pr3 = s1 ? o8 : o3;
    float pr4 = s1 ? o9 : o4;
    float po4 = s1 ? o4 : o9;

    float gr0 = s1 ? g5 : g0;
    float gr1 = s1 ? g6 : g1;
    float gr2 = s1 ? g7 : g2;
    float gr3 = s1 ? g8 : g3;
    float gn4 = s1 ? g4 : g9;

    float d4 = o4 - g4, d9 = o9 - g9;
    float no_loss = noobj * (d4 * d4 + d9 * d9);

    float dcf  = pr4 - max_iou;
    float conf = dcf * dcf;

    float l0 = pr0 - gr0, l1 = pr1 - gr1, l2 = pr2 - gr2, l3 = pr3 - gr3;
    float loc = l0 * l0 + l1 * l1 + l2 * l2 + l3 * l3;

    float dnb = po4 - gn4;
    float nbc = dnb * dnb;

    float cls = 0.0f;
#pragma unroll
    for (int c = 10; c < 14; ++c) { float d = o[c] - g[c]; cls += d * d; }

    return LAMBDA_NOOBJ * no_loss +
           obj * (conf + LAMBDA_COORD * loc + LAMBDA_NOOBJ * nbc + LAMBDA_CLASS * cls);
}

__global__ __launch_bounds__(64) void yolo_partial(const float* __restrict__ outp,
                                                   const float* __restrict__ gtp,
                                                   float* __restrict__ partial) {
    // 2 LDS buffers, each [O: 448 float4 | G: 448 float4] = 28672 B total
    __shared__ float4 sbuf[2][2 * kChunkVec4];

    const int lane = threadIdx.x;                 // block = exactly 1 wave
    const int slot = blockIdx.x;

    const float4* bO = reinterpret_cast<const float4*>(outp) + (size_t)slot * kChunksSlot * kChunkVec4;
    const float4* bG = reinterpret_cast<const float4*>(gtp)  + (size_t)slot * kChunksSlot * kChunkVec4;

    // Register chunk buffer: 14 float4 = 56 VGPRs, all loads live simultaneously.
    float4 r[14];

    // Issue 14 coalesced dwordx4 loads for chunk c into r (no waits here).
    auto issue = [&](int c) {
        const float4* pO = bO + c * kChunkVec4;
        const float4* pG = bG + c * kChunkVec4;
#pragma unroll
        for (int k = 0; k < 7; ++k) r[k]     = pO[k * 64 + lane];
#pragma unroll
        for (int k = 0; k < 7; ++k) r[7 + k] = pG[k * 64 + lane];
    };

    // ds_write r into LDS buffer b (compiler inserts precise vmcnt waits on r).
    auto stash = [&](int b) {
        float4* lO = sbuf[b];
        float4* lG = sbuf[b] + kChunkVec4;
#pragma unroll
        for (int k = 0; k < 7; ++k) lO[k * 64 + lane] = r[k];
#pragma unroll
        for (int k = 0; k < 7; ++k) lG[k * 64 + lane] = r[7 + k];
    };

    // Prologue: chunk0 -> buf0; chunk1 loads left in flight in r.
    issue(0);
    stash(0);
    issue(1);

    float loss = 0.0f;

    for (int c = 0; c < kChunksSlot; ++c) {
        // Compute chunk c from LDS while chunk c+1's loads stream into r.
        const float* f = reinterpret_cast<const float*>(sbuf[c & 1]);
        const float* gf = f + kChunkFlts;
        loss += cell_loss(f + lane * kC,        gf + lane * kC);
        loss += cell_loss(f + (lane + 64) * kC, gf + (lane + 64) * kC);

        // Retire chunk c+1 into the other buffer, then refill r with chunk c+2.
        // DS ops are in-order per wave: these writes cannot pass the reads above.
        if (c + 1 < kChunksSlot) stash((c + 1) & 1);
        if (c + 2 < kChunksSlot) issue(c + 2);
    }

    // wave64 tree reduce; one partial per wave-slot, no barriers anywhere
#pragma unroll
    for (int off = 32; off > 0; off >>= 1) loss += __shfl_down(loss, off, 64);
    if (lane == 0) partial[slot] = loss;
}

__global__ __launch_bounds__(256) void yolo_final(const float* __restrict__ partial,
                                                  float* __restrict__ out) {
    __shared__ double red[4];
    double acc = 0.0;
    for (int i = threadIdx.x; i < kSlots; i += 256) acc += (double)partial[i];
#pragma unroll
    for (int off = 32; off > 0; off >>= 1) acc += __shfl_down(acc, off, 64);
    int tid = threadIdx.x;
    if ((tid & 63) == 0) red[tid >> 6] = acc;
    __syncthreads();
    if (tid == 0) out[0] = (float)((red[0] + red[1] + red[2] + red[3]) * (1.0 / (double)kN));
}

extern "C" void kernel_launch(void* const* d_in, const int* in_sizes, int n_in,
                              void* d_out, int out_size, void* d_ws, size_t ws_size,
                              hipStream_t stream) {
    const float* outp = (const float*)d_in[0];   // output: (N,H,W,C) fp32
    const float* gtp  = (const float*)d_in[1];   // ground_truth: (N,H,W,C) fp32
    float* partial    = (float*)d_ws;            // 1024 floats = 4 KB scratch
    float* out        = (float*)d_out;

    yolo_partial<<<kSlots, 64, 0, stream>>>(outp, gtp, partial);
    yolo_final<<<1, 256, 0, stream>>>(partial, out);
}

// Round 6
// 215.980 us; speedup vs baseline: 1.0079x; 1.0079x over previous
//
#include <hip/hip_runtime.h>
#include <stdint.h>

// Problem constants (from reference): N=32768, H=6, W=8, C=14
constexpr int   kN          = 32768;
constexpr int   kCells      = 32768 * 6 * 8;      // 1,572,864 cells, 14 floats each
constexpr int   kC          = 14;

// Double-buffered LDS staging, raw-barrier pipeline:
//   chunk = 256 cells = 3584 floats/tensor = 896 float4/tensor (O + G = 28672 B)
//   LDS = 2 x 28672 B buffers = 57344 B -> 2 blocks/CU (8 waves/CU)
//   block = 256 threads; per thread per chunk: <=4+4 float4 = 32 VGPR relay buffer
//   grid = 512 blocks x 12 chunks x 256 cells = 1,572,864 = kCells (exact)
constexpr int   kChunkCells = 256;
constexpr int   kChunkFlts  = kChunkCells * kC;        // 3584 floats per tensor
constexpr int   kChunkVec4  = kChunkFlts / 4;          // 896 float4 per tensor
constexpr int   kChunks     = 12;
constexpr int   kBlocks     = 512;

constexpr float LAMBDA_COORD = 8.0f;
constexpr float LAMBDA_NOOBJ = 1.0f;
constexpr float LAMBDA_CLASS = 0.7f;
constexpr float EPS          = 1e-10f;

// s_waitcnt immediate: lgkmcnt(0), vmcnt/expcnt = no-wait (verified in R3)
#define WAITCNT_LGKM0  0xc07f

__device__ __forceinline__ float iou_box(float bx, float by, float bsw, float bsh,
                                         float gx, float gy, float gsw, float gsh) {
    float w1 = bsw * bsw, h1 = bsh * bsh;
    float w2 = gsw * gsw, h2 = gsh * gsh;
    float left  = fmaxf(bx - 0.5f * w1, gx - 0.5f * w2);
    float right = fminf(bx + 0.5f * w1, gx + 0.5f * w2);
    float top   = fmaxf(by - 0.5f * h1, gy - 0.5f * h2);
    float bot   = fminf(by + 0.5f * h1, gy + 0.5f * h2);
    float inter = fmaxf(right - left, 0.0f) * fmaxf(bot - top, 0.0f);
    float uni   = w1 * h1 + w2 * h2 - inter;
    return inter / (uni + EPS);
}

__device__ __forceinline__ float cell_loss(const float* __restrict__ o,
                                           const float* __restrict__ g) {
    float o0=o[0],o1=o[1],o2=o[2],o3=o[3],o4=o[4],o5=o[5],o6=o[6],o7=o[7],o8=o[8],o9=o[9];
    float g0=g[0],g1=g[1],g2=g[2],g3=g[3],g4=g[4],g5=g[5],g6=g[6],g7=g[7],g8=g[8],g9=g[9];

    float obj   = (g4 > 0.0f) ? 1.0f : 0.0f;
    float noobj = 1.0f - obj;

    float iou0 = iou_box(o0, o1, o2, o3, g0, g1, g2, g3);
    float iou1 = iou_box(o5, o6, o7, o8, g0, g1, g2, g3);
    bool  s1   = iou1 > iou0;                  // argmax picks first on ties
    float max_iou = fmaxf(iou0, iou1);

    float pr0 = s1 ? o5 : o0;
    float pr1 = s1 ? o6 : o1;
    float pr2 = s1 ? o7 : o2;
    float pr3 = s1 ? o8 : o3;
    float pr4 = s1 ? o9 : o4;
    float po4 = s1 ? o4 : o9;

    float gr0 = s1 ? g5 : g0;
    float gr1 = s1 ? g6 : g1;
    float gr2 = s1 ? g7 : g2;
    float gr3 = s1 ? g8 : g3;
    float gn4 = s1 ? g4 : g9;

    float d4 = o4 - g4, d9 = o9 - g9;
    float no_loss = noobj * (d4 * d4 + d9 * d9);

    float dcf  = pr4 - max_iou;
    float conf = dcf * dcf;

    float l0 = pr0 - gr0, l1 = pr1 - gr1, l2 = pr2 - gr2, l3 = pr3 - gr3;
    float loc = l0 * l0 + l1 * l1 + l2 * l2 + l3 * l3;

    float dnb = po4 - gn4;
    float nbc = dnb * dnb;

    float cls = 0.0f;
#pragma unroll
    for (int c = 10; c < 14; ++c) { float d = o[c] - g[c]; cls += d * d; }

    return LAMBDA_NOOBJ * no_loss +
           obj * (conf + LAMBDA_COORD * loc + LAMBDA_NOOBJ * nbc + LAMBDA_CLASS * cls);
}

__global__ __launch_bounds__(256, 2) void yolo_partial(const float* __restrict__ outp,
                                                       const float* __restrict__ gtp,
                                                       float* __restrict__ partial) {
    // two staging buffers, each [O: 896 float4 | G: 896 float4] = 28672 B
    __shared__ float4 sbuf[2][2 * kChunkVec4];
    __shared__ float  red[4];

    const int tid = threadIdx.x;
    const int blk = blockIdx.x;

    const float4* bO = reinterpret_cast<const float4*>(outp) + (size_t)blk * kChunks * kChunkVec4;
    const float4* bG = reinterpret_cast<const float4*>(gtp)  + (size_t)blk * kChunks * kChunkVec4;

    // Small relay buffer: 8 float4 = 32 VGPRs — too small to throttle or spill.
    float4 rO[4], rG[4];

    // Issue per-instruction-contiguous loads for chunk c (no waits emitted here).
    // 896 = 3*256 + 128: k=3 is taken by waves 0-1 only (wave-uniform, no divergence).
    auto issue = [&](int c) {
        const float4* pO = bO + c * kChunkVec4;
        const float4* pG = bG + c * kChunkVec4;
#pragma unroll
        for (int k = 0; k < 3; ++k) rO[k] = pO[k * 256 + tid];
        if (tid < 128) rO[3] = pO[768 + tid];
#pragma unroll
        for (int k = 0; k < 3; ++k) rG[k] = pG[k * 256 + tid];
        if (tid < 128) rG[3] = pG[768 + tid];
    };

    // ds_write relay regs into buffer b; HW waits (precisely) on just these loads.
    auto stash = [&](int b) {
        float4* lO = &sbuf[b][0];
        float4* lG = &sbuf[b][kChunkVec4];
#pragma unroll
        for (int k = 0; k < 3; ++k) lO[k * 256 + tid] = rO[k];
        if (tid < 128) lO[768 + tid] = rO[3];
#pragma unroll
        for (int k = 0; k < 3; ++k) lG[k * 256 + tid] = rG[k];
        if (tid < 128) lG[768 + tid] = rG[3];
    };

    // Raw barrier: lgkmcnt(0) only — global loads keep streaming across it.
    auto lds_barrier = [&]() {
        __builtin_amdgcn_s_waitcnt(WAITCNT_LGKM0);
        __builtin_amdgcn_s_barrier();
    };

    // Prologue: chunk0 staged; chunk1 in flight in regs.
    issue(0);
    stash(0);
    issue(1);
    lds_barrier();

    float loss = 0.0f;

    for (int c = 0; c < kChunks; ++c) {
        // Compute chunk c (1 cell per thread) from LDS.
        const float* f  = reinterpret_cast<const float*>(&sbuf[c & 1][0]);
        const float* gf = f + kChunkFlts;
        loss += cell_loss(f + tid * kC, gf + tid * kC);

        if (c + 1 < kChunks) {
            stash((c + 1) & 1);          // waits only on chunk c+1's 8 loads
            if (c + 2 < kChunks) issue(c + 2);   // next chunk streams over barrier
            lds_barrier();
        }
    }

    // Block reduction (cold path — a full __syncthreads here is fine).
#pragma unroll
    for (int off = 32; off > 0; off >>= 1) loss += __shfl_down(loss, off, 64);
    if ((tid & 63) == 0) red[tid >> 6] = loss;
    __syncthreads();
    if (tid == 0) partial[blk] = red[0] + red[1] + red[2] + red[3];
}

__global__ __launch_bounds__(256) void yolo_final(const float* __restrict__ partial,
                                                  float* __restrict__ out) {
    __shared__ double red[4];
    double acc = 0.0;
    for (int i = threadIdx.x; i < kBlocks; i += 256) acc += (double)partial[i];
#pragma unroll
    for (int off = 32; off > 0; off >>= 1) acc += __shfl_down(acc, off, 64);
    int tid = threadIdx.x;
    if ((tid & 63) == 0) red[tid >> 6] = acc;
    __syncthreads();
    if (tid == 0) out[0] = (float)((red[0] + red[1] + red[2] + red[3]) * (1.0 / (double)kN));
}

extern "C" void kernel_launch(void* const* d_in, const int* in_sizes, int n_in,
                              void* d_out, int out_size, void* d_ws, size_t ws_size,
                              hipStream_t stream) {
    const float* outp = (const float*)d_in[0];   // output: (N,H,W,C) fp32
    const float* gtp  = (const float*)d_in[1];   // ground_truth: (N,H,W,C) fp32
    float* partial    = (float*)d_ws;            // 512 floats = 2 KB scratch
    float* out        = (float*)d_out;

    yolo_partial<<<kBlocks, 256, 0, stream>>>(outp, gtp, partial);
    yolo_final<<<1, 256, 0, stream>>>(partial, out);
}